// Round 10
// baseline (291.848 us; speedup 1.0000x reference)
//
#include <hip/hip_runtime.h>
#include <hip/hip_bf16.h>
#include <cstdint>
#include <cstddef>

typedef __bf16 bf16_t;
typedef __attribute__((ext_vector_type(4))) __bf16 bf16x4;
typedef __attribute__((ext_vector_type(8))) __bf16 bf16x8;
typedef __attribute__((ext_vector_type(4))) float f32x4;

#define MFMA16(a, b, c) __builtin_amdgcn_mfma_f32_16x16x32_bf16(a, b, c, 0, 0, 0)

constexpr int LSEQ = 2048;
constexpr int DMODEL = 512;
constexpr int NHEAD = 8;
constexpr int DKH = 64;
constexpr float INV_TEMPER = 0.04419417382415922f;  // 1/sqrt(512)

// ------------------------------------------- transpose+cast W [K][N] f32 -> Wt [N][K] bf16
__global__ __launch_bounds__(256) void k_transpose_cast(const float* __restrict__ in,
                                                        bf16_t* __restrict__ out,
                                                        int K, int N) {
    __shared__ float tile[32][33];
    int n0 = blockIdx.x * 32, k0 = blockIdx.y * 32;
    int tx = threadIdx.x, ty = threadIdx.y;
#pragma unroll
    for (int i = 0; i < 4; i++)
        tile[ty + i * 8][tx] = in[(size_t)(k0 + ty + i * 8) * N + n0 + tx];
    __syncthreads();
#pragma unroll
    for (int i = 0; i < 4; i++)
        out[(size_t)(n0 + ty + i * 8) * K + k0 + tx] = (bf16_t)tile[tx][ty + i * 8];
}

// ------------------------------------------- NT GEMM: C[m][n] = A[m][:]·Bt[n][:] + bias
// MODE 0: A f32 (cast in staging); Q -> Qh (scaled), K -> Kh, V -> Vtp (transposed +
//         within-32 k-slot permutation: location 32c+8hq+e holds V[32c+perm(hq,e)]).
// MODE 1: A bf16; f32 out (final projection).
template <int MODE>
__global__ __launch_bounds__(256) void k_gemm_nt(const void* __restrict__ Av,
                                                 const bf16_t* __restrict__ Bt,
                                                 const float* __restrict__ bias,
                                                 bf16_t* __restrict__ outQ,
                                                 bf16_t* __restrict__ outK,
                                                 bf16_t* __restrict__ outV,
                                                 float* __restrict__ outO, int K) {
    __shared__ bf16_t As[128 * 32];
    __shared__ bf16_t Bs[128 * 32];
    int t = threadIdx.x;
    int lane = t & 63, w = t >> 6;
    int wm = w >> 1, wn = w & 1;
    int rr = lane & 15, hq = lane >> 4;
    int m0 = blockIdx.x * 128, n0 = blockIdx.y * 128;
    int srow = t >> 2, sseg = t & 3;
    const float* gaF = (const float*)Av + (size_t)(m0 + srow) * K + sseg * 8;
    const bf16_t* gaB = (const bf16_t*)Av + (size_t)(m0 + srow) * K + sseg * 8;
    const bf16_t* gb = Bt + (size_t)(n0 + srow) * K + sseg * 8;
    f32x4 acc[4][4] = {};
    for (int k0 = 0; k0 < K; k0 += 32) {
        bf16x8 a0, a1;
        if (MODE == 0) {
            float4 l0 = *reinterpret_cast<const float4*>(gaF + k0);
            float4 h0 = *reinterpret_cast<const float4*>(gaF + k0 + 4);
            float4 l1 = *reinterpret_cast<const float4*>(gaF + (size_t)64 * K + k0);
            float4 h1 = *reinterpret_cast<const float4*>(gaF + (size_t)64 * K + k0 + 4);
            a0[0] = (bf16_t)l0.x; a0[1] = (bf16_t)l0.y; a0[2] = (bf16_t)l0.z; a0[3] = (bf16_t)l0.w;
            a0[4] = (bf16_t)h0.x; a0[5] = (bf16_t)h0.y; a0[6] = (bf16_t)h0.z; a0[7] = (bf16_t)h0.w;
            a1[0] = (bf16_t)l1.x; a1[1] = (bf16_t)l1.y; a1[2] = (bf16_t)l1.z; a1[3] = (bf16_t)l1.w;
            a1[4] = (bf16_t)h1.x; a1[5] = (bf16_t)h1.y; a1[6] = (bf16_t)h1.z; a1[7] = (bf16_t)h1.w;
        } else {
            a0 = *reinterpret_cast<const bf16x8*>(gaB + k0);
            a1 = *reinterpret_cast<const bf16x8*>(gaB + (size_t)64 * K + k0);
        }
        uint4 b0 = *reinterpret_cast<const uint4*>(gb + k0);
        uint4 b1 = *reinterpret_cast<const uint4*>(gb + (size_t)64 * K + k0);
        __syncthreads();
        *reinterpret_cast<bf16x8*>(&As[srow * 32 + sseg * 8]) = a0;
        *reinterpret_cast<bf16x8*>(&As[(srow + 64) * 32 + sseg * 8]) = a1;
        *reinterpret_cast<uint4*>(&Bs[srow * 32 + sseg * 8]) = b0;
        *reinterpret_cast<uint4*>(&Bs[(srow + 64) * 32 + sseg * 8]) = b1;
        __syncthreads();
        bf16x8 af[4], bff[4];
#pragma unroll
        for (int i = 0; i < 4; i++) {
            af[i] = *reinterpret_cast<const bf16x8*>(&As[(wm * 64 + i * 16 + rr) * 32 + hq * 8]);
            bff[i] = *reinterpret_cast<const bf16x8*>(&Bs[(wn * 64 + i * 16 + rr) * 32 + hq * 8]);
        }
#pragma unroll
        for (int mi = 0; mi < 4; mi++)
#pragma unroll
            for (int ni = 0; ni < 4; ni++)
                acc[mi][ni] = MFMA16(af[mi], bff[ni], acc[mi][ni]);
    }
    // epilogue (C/D layout: col = lane&15, row = 4*(lane>>4)+reg  [verified in-harness r6/r7])
#pragma unroll
    for (int mi = 0; mi < 4; mi++) {
#pragma unroll
        for (int ni = 0; ni < 4; ni++) {
            int gn = n0 + wn * 64 + ni * 16 + rr;
            float bv = bias[gn];
            int gmb = m0 + wm * 64 + mi * 16 + hq * 4;
            if (MODE == 0) {
                int which = gn >> 9;        // 0=q 1=k 2=v
                int hn = (gn >> 6) & 7;     // head
                int dk = gn & 63;
                if (which == 2) {
                    // V -> Vtp[bh][dk][pos]; pos formula: within each 32-token group,
                    // location 8hq+e holds token perm(hq,e) = (e<4 ? 4hq+e : 16+4hq+e-4)
#pragma unroll
                    for (int rg = 0; rg < 4; rg++) {
                        int gm = gmb + rg;
                        int bb = gm >> 11, ll = gm & 2047;
                        int pos = (ll & ~31) | ((ll & 0xC) << 1) | ((ll & 0x10) >> 2) | (ll & 3);
                        outV[(((size_t)bb * NHEAD + hn) * DKH + dk) * LSEQ + pos] =
                            (bf16_t)(acc[mi][ni][rg] + bv);
                    }
                } else {
                    bf16_t* dst = which == 0 ? outQ : outK;
                    float scale = which == 0 ? INV_TEMPER : 1.0f;
#pragma unroll
                    for (int rg = 0; rg < 4; rg++) {
                        int gm = gmb + rg;
                        int bb = gm >> 11, ll = gm & 2047;
                        float v = (acc[mi][ni][rg] + bv) * scale;
                        dst[(((size_t)bb * NHEAD + hn) * LSEQ + ll) * DKH + dk] = (bf16_t)v;
                    }
                }
            } else {
#pragma unroll
                for (int rg = 0; rg < 4; rg++) {
                    int gm = gmb + rg;
                    outO[(size_t)gm * DMODEL + gn] = acc[mi][ni][rg] + bv;
                }
            }
        }
    }
}

// ------------------------------------------- fused attention v4: no shuffles, no staging
// Per block (h, b, 16 q-rows). Swapped QK^T (A=K, B=Q): lane (rr,hq) reg i holds
// S[q0+rr][cb+4hq+i]. Rowsums via padded-LDS reduce (no shfl). PV with operands
// swapped back (A=Vtp permuted, B=P registers as-is): lane's P regs are already the
// exact B-fragment -> zero cross-lane movement. D = O[q0+rr][16nt+4hq+i].
__global__ __launch_bounds__(256) void k_attn4(const bf16_t* __restrict__ Qh,
                                               const bf16_t* __restrict__ Kh,
                                               const bf16_t* __restrict__ Vtp,
                                               const int* __restrict__ mask,
                                               float* __restrict__ attn_out,
                                               bf16_t* __restrict__ Obf) {
    __shared__ float sO[4 * 16 * 65];   // per-wave O partials, padded stride 65
    __shared__ float rpart[16 * 17];    // [row rr][w*4+hq], padded stride 17
    int t = threadIdx.x;
    int lane = t & 63, w = t >> 6;
    int rr = lane & 15, hq = lane >> 4;
    int bid = blockIdx.x;
    int h = bid & 7, b = (bid >> 3) & 1, qt = bid >> 4;
    int q0 = qt * 16;
    int bh = b * NHEAD + h;

    // Q fragments (rows q0..q0+15, d-slots hq*8..+7; two 32-k steps)
    const bf16_t* qp = Qh + ((size_t)bh * LSEQ + q0 + rr) * DKH + hq * 8;
    bf16x8 qf0 = *reinterpret_cast<const bf16x8*>(qp);
    bf16x8 qf1 = *reinterpret_cast<const bf16x8*>(qp + 32);

    const bf16_t* kb = Kh + (size_t)bh * LSEQ * DKH;
    const int* mrow = mask + ((size_t)b * LSEQ + q0 + rr) * LSEQ;

    // ---- pass A: row sums (nothing stored). Wave w: cols [w*512, w*512+512)
    float rs = 0.f;
#pragma unroll 4
    for (int nt = 0; nt < 32; nt++) {
        int cb = w * 512 + nt * 16;
        const bf16_t* kp = kb + (size_t)(cb + rr) * DKH + hq * 8;
        bf16x8 kf0 = *reinterpret_cast<const bf16x8*>(kp);
        bf16x8 kf1 = *reinterpret_cast<const bf16x8*>(kp + 32);
        f32x4 acc = {0.f, 0.f, 0.f, 0.f};
        acc = MFMA16(kf0, qf0, acc);   // swapped: D[i] = S[q0+rr][cb+4*hq+i]
        acc = MFMA16(kf1, qf1, acc);
        int4 mv = *reinterpret_cast<const int4*>(mrow + cb + hq * 4);
        // no max-subtraction: scores O(1); masked -> 0 exactly as reference
        rs += mv.x ? 0.f : __expf(acc[0]);
        rs += mv.y ? 0.f : __expf(acc[1]);
        rs += mv.z ? 0.f : __expf(acc[2]);
        rs += mv.w ? 0.f : __expf(acc[3]);
    }
    // shuffle-free reduce: 16 partials per row (4 waves x 4 hq groups) via LDS
    rpart[rr * 17 + w * 4 + hq] = rs;
    __syncthreads();
    float sum = 0.f;
#pragma unroll
    for (int j = 0; j < 16; j++) sum += rpart[rr * 17 + j];
    float invr = 1.0f / sum;

    // ---- pass B: recompute -> normalized P in regs -> attns write + swapped PV
    const bf16_t* vb = Vtp + (size_t)bh * DKH * LSEQ;
    float* arow = attn_out + ((size_t)(h * 2 + b) * LSEQ + q0 + rr) * LSEQ;
    f32x4 osum[4] = {};
#pragma unroll 2
    for (int nt2 = 0; nt2 < 16; nt2++) {
        int cb0 = w * 512 + nt2 * 32;
        const bf16_t* kp0 = kb + (size_t)(cb0 + rr) * DKH + hq * 8;
        const bf16_t* kp1 = kb + (size_t)(cb0 + 16 + rr) * DKH + hq * 8;
        bf16x8 kf00 = *reinterpret_cast<const bf16x8*>(kp0);
        bf16x8 kf01 = *reinterpret_cast<const bf16x8*>(kp0 + 32);
        bf16x8 kf10 = *reinterpret_cast<const bf16x8*>(kp1);
        bf16x8 kf11 = *reinterpret_cast<const bf16x8*>(kp1 + 32);
        f32x4 a0 = {0.f, 0.f, 0.f, 0.f}, a1 = {0.f, 0.f, 0.f, 0.f};
        a0 = MFMA16(kf00, qf0, a0); a0 = MFMA16(kf01, qf1, a0);
        a1 = MFMA16(kf10, qf0, a1); a1 = MFMA16(kf11, qf1, a1);
        int4 m0 = *reinterpret_cast<const int4*>(mrow + cb0 + hq * 4);
        int4 m1 = *reinterpret_cast<const int4*>(mrow + cb0 + 16 + hq * 4);
        float p0 = m0.x ? 0.f : __expf(a0[0]) * invr;
        float p1 = m0.y ? 0.f : __expf(a0[1]) * invr;
        float p2 = m0.z ? 0.f : __expf(a0[2]) * invr;
        float p3 = m0.w ? 0.f : __expf(a0[3]) * invr;
        float p4 = m1.x ? 0.f : __expf(a1[0]) * invr;
        float p5 = m1.y ? 0.f : __expf(a1[1]) * invr;
        float p6 = m1.z ? 0.f : __expf(a1[2]) * invr;
        float p7 = m1.w ? 0.f : __expf(a1[3]) * invr;
        // attns: lane (rr,hq) holds row q0+rr, cols cb0+4hq+i and cb0+16+4hq+i
        float4 w0 = {p0, p1, p2, p3}, w1 = {p4, p5, p6, p7};
        *reinterpret_cast<float4*>(arow + cb0 + hq * 4) = w0;
        *reinterpret_cast<float4*>(arow + cb0 + 16 + hq * 4) = w1;
        // PV swapped: A = Vtp (slot e holds V[cb0+perm(hq,e)][d]),
        //             B = P regs (slot e holds P[q0+rr][cb0+perm(hq,e)]) -> same k ✓
        bf16x8 pa;
        pa[0] = (bf16_t)p0; pa[1] = (bf16_t)p1; pa[2] = (bf16_t)p2; pa[3] = (bf16_t)p3;
        pa[4] = (bf16_t)p4; pa[5] = (bf16_t)p5; pa[6] = (bf16_t)p6; pa[7] = (bf16_t)p7;
#pragma unroll
        for (int ntile = 0; ntile < 4; ntile++) {
            bf16x8 vf = *reinterpret_cast<const bf16x8*>(
                vb + (size_t)(ntile * 16 + rr) * LSEQ + cb0 + hq * 8);
            osum[ntile] = MFMA16(vf, pa, osum[ntile]);  // D[4hq+i][rr] = O[q0+rr][16nt+4hq+i]
        }
    }
    // cross-wave O reduce: lane (rr,hq) holds O[q0+rr][d = 16*ntile + 4hq + i]
#pragma unroll
    for (int ntile = 0; ntile < 4; ntile++)
#pragma unroll
        for (int i = 0; i < 4; i++)
            sO[w * 1040 + rr * 65 + ntile * 16 + hq * 4 + i] = osum[ntile][i];
    __syncthreads();
#pragma unroll
    for (int i = 0; i < 4; i++) {
        int e = i * 256 + t;
        int orow = e >> 6, oc = e & 63;
        float v = sO[orow * 65 + oc] + sO[1040 + orow * 65 + oc] +
                  sO[2080 + orow * 65 + oc] + sO[3120 + orow * 65 + oc];
        Obf[(((size_t)b * LSEQ + q0 + orow) * NHEAD + h) * DKH + oc] = (bf16_t)v;
    }
}

// ----------------------------------------------------------------------- launch
extern "C" void kernel_launch(void* const* d_in, const int* in_sizes, int n_in,
                              void* d_out, int out_size, void* d_ws, size_t ws_size,
                              hipStream_t stream) {
    (void)in_sizes; (void)n_in; (void)out_size; (void)ws_size;
    const float* q = (const float*)d_in[0];
    const int* mask = (const int*)d_in[3];   // int32 (verified r6)
    const float* W_qkv = (const float*)d_in[4];
    const float* b_qkv = (const float*)d_in[5];
    const float* W_proj = (const float*)d_in[6];
    const float* b_proj = (const float*)d_in[7];
    float* out = (float*)d_out;
    float* attn_out = out + (size_t)2 * LSEQ * DMODEL;  // f32 elements

    char* ws = (char*)d_ws;
    bf16_t* wqkv_t = (bf16_t*)(ws);                   // 1.5 MB
    bf16_t* wproj_t = (bf16_t*)(ws + 1572864);        // 0.5 MB
    bf16_t* Qh = (bf16_t*)(ws + 2097152);             // 4 MB
    bf16_t* Kh = (bf16_t*)(ws + 6291456);             // 4 MB
    bf16_t* Vtp = (bf16_t*)(ws + 10485760);           // 4 MB
    bf16_t* Obf = (bf16_t*)(ws + 14680064);           // 4 MB  (total 18 MB)

    k_transpose_cast<<<dim3(48, 16), dim3(32, 8), 0, stream>>>(W_qkv, wqkv_t, 512, 1536);
    k_transpose_cast<<<dim3(16, 16), dim3(32, 8), 0, stream>>>(W_proj, wproj_t, 512, 512);
    k_gemm_nt<0><<<dim3(32, 12), 256, 0, stream>>>(q, wqkv_t, b_qkv, Qh, Kh, Vtp, nullptr, 512);
    k_attn4<<<2048, 256, 0, stream>>>(Qh, Kh, Vtp, mask, attn_out, Obf);
    k_gemm_nt<1><<<dim3(32, 4), 256, 0, stream>>>(Obf, wproj_t, b_proj, nullptr, nullptr, nullptr, out, 512);
}